// Round 2
// baseline (566.422 us; speedup 1.0000x reference)
//
#include <hip/hip_runtime.h>
#include <hip/hip_bf16.h>

typedef unsigned short u16;
typedef __bf16 bf16x8 __attribute__((ext_vector_type(8)));
typedef float f32x4 __attribute__((ext_vector_type(4)));

#define NROWS 32768
#define H 512
#define NS 8
#define NR 64
#define NT 12

// workspace layout (bytes)
#define WS_W1T   0            // [8][512][512] bf16 = 4194304
#define WS_UCT   4194304      // [512][512] bf16    = 524288
#define WS_W2T   4718592      // [8][16][512] bf16  = 131072
#define WS_CVEC  4849664      // [8][64] f32        = 2048

union BFU { __bf16 h; u16 u; };
__device__ __forceinline__ u16 f2bf(float v) { BFU b; b.h = (__bf16)v; return b.u; }

// ---------- prep: batched transpose + cast to bf16, out[b][c][r] = in[b][r][c] (c<Cc else 0) ----------
__global__ __launch_bounds__(256) void transpose_cast(const float* __restrict__ in,
    u16* __restrict__ out, int Rr, int Cc, int Cpad) {
  __shared__ float tile[32][33];
  int b = blockIdx.z, r0 = blockIdx.x * 32, c0 = blockIdx.y * 32;
  int tx = threadIdx.x, ty = threadIdx.y;
#pragma unroll
  for (int i = 0; i < 4; i++) {
    int r = r0 + ty + i * 8, c = c0 + tx;
    float v = 0.f;
    if (r < Rr && c < Cc) v = in[((size_t)b * Rr + r) * Cc + c];
    tile[ty + i * 8][tx] = v;
  }
  __syncthreads();
#pragma unroll
  for (int i = 0; i < 4; i++) {
    int c = c0 + ty + i * 8, r = r0 + tx;
    if (c < Cpad && r < Rr) out[((size_t)b * Cpad + c) * Rr + r] = f2bf(tile[tx][ty + i * 8]);
  }
}

// ---------- prep: c[s][r] = sum_k mu[s][k] * Us[s][k][r], one block per (s,r) ----------
__global__ __launch_bounds__(64) void compute_c(const float* __restrict__ mu,
                                                const float* __restrict__ Us,
                                                float* __restrict__ cvec) {
  int s = blockIdx.x >> 6, r = blockIdx.x & 63, t = threadIdx.x;
  float acc = 0.f;
#pragma unroll
  for (int k = t; k < H; k += 64) acc += mu[s * H + k] * Us[((size_t)s * H + k) * NR + r];
#pragma unroll
  for (int m = 32; m; m >>= 1) acc += __shfl_xor(acc, m, 64);
  if (t == 0) cvec[blockIdx.x] = acc;
}

// ---------- helpers for main kernel (256 threads) ----------
__device__ __forceinline__ void stage64x256(u16* Wst, const u16* g, int tid) {
  // copy 64 rows x 256 bf16 (row stride 512 in global) into LDS rows of stride 264
#pragma unroll
  for (int i = 0; i < 8; i++) {
    int u = tid + i * 256;
    int n = u >> 5, kk = (u & 31) * 8;
    *(uint4*)&Wst[n * 264 + kk] = *(const uint4*)&g[n * 512 + kk];
  }
}

__device__ __forceinline__ void mfma_half(const u16* Wst, const bf16x8 (*af)[16], int half,
                                          int lnm, int lnq, f32x4 acc[2][4]) {
#pragma unroll
  for (int ks = 0; ks < 8; ks++) {
    bf16x8 b[4];
#pragma unroll
    for (int ct = 0; ct < 4; ct++)
      b[ct] = *(const bf16x8*)&Wst[(ct * 16 + lnm) * 264 + ks * 32 + lnq * 8];
#pragma unroll
    for (int ct = 0; ct < 4; ct++) {
#pragma unroll
      for (int t = 0; t < 2; t++)
        acc[t][ct] = __builtin_amdgcn_mfma_f32_16x16x32_bf16(af[t][half * 8 + ks], b[ct],
                                                             acc[t][ct], 0, 0, 0);
    }
  }
}

// ---------- main fused kernel: 4 waves x 2 m-tiles = 128 rows per block ----------
__global__ __launch_bounds__(256, 2) void moe_main(
    const float* __restrict__ enc, const u16* __restrict__ W1T,
    const u16* __restrict__ UcatT, const u16* __restrict__ W2T,
    const float* __restrict__ cvec, const float* __restrict__ b1g,
    const float* __restrict__ b2g, float* __restrict__ out) {
  __shared__ __align__(16) u16 Wst[64 * 264];    // 33792 B weight half-chunk
  __shared__ __align__(16) u16 h1c[128 * 72];    // 18432 B h1 chunk (pad 64->72)
  __shared__ float b1s[H];                       // 2048 B
  __shared__ float distS[NS][128];               // 4096 B
  __shared__ float alphS[NS][128];               // 4096 B
  __shared__ float cst[NS * NR];                 // 2048 B   (total 64512 B -> 2 blocks/CU)

  const int tid = threadIdx.x;
  const int wave = tid >> 6, lane = tid & 63;
  const int lnm = lane & 15, lnq = lane >> 4;
  const int row0 = blockIdx.x * 128;

  cst[tid] = cvec[tid];
  cst[tid + 256] = cvec[tid + 256];

  // load A fragments (raw encodings, bf16) into registers: 2 m-tiles x 16 k-steps x 8
  bf16x8 afrag[2][16];
#pragma unroll
  for (int t = 0; t < 2; t++) {
    const float* rp = enc + (size_t)(row0 + wave * 32 + t * 16 + lnm) * H + lnq * 8;
#pragma unroll
    for (int ks = 0; ks < 16; ks++) {
      float4 x0 = *(const float4*)(rp + ks * 32);
      float4 x1 = *(const float4*)(rp + ks * 32 + 4);
      bf16x8 a;
      a[0] = (__bf16)x0.x; a[1] = (__bf16)x0.y; a[2] = (__bf16)x0.z; a[3] = (__bf16)x0.w;
      a[4] = (__bf16)x1.x; a[5] = (__bf16)x1.y; a[6] = (__bf16)x1.z; a[7] = (__bf16)x1.w;
      afrag[t][ks] = a;
    }
  }

  // ---------------- routing: dist[s][row] = ||enc@Us[s] - c[s]|| ----------------
#pragma unroll 1
  for (int s2 = 0; s2 < NS; s2++) {
    f32x4 acc[2][4] = {};
    const u16* ub = UcatT + (size_t)s2 * 64 * H;
    __syncthreads();
    stage64x256(Wst, ub, tid);
    __syncthreads();
    mfma_half(Wst, afrag, 0, lnm, lnq, acc);
    __syncthreads();
    stage64x256(Wst, ub + 256, tid);
    __syncthreads();
    mfma_half(Wst, afrag, 1, lnm, lnq, acc);

#pragma unroll
    for (int t = 0; t < 2; t++) {
      float dsq[4] = {0.f, 0.f, 0.f, 0.f};
#pragma unroll
      for (int ct = 0; ct < 4; ct++) {
        float cv = cst[s2 * 64 + ct * 16 + lnm];
#pragma unroll
        for (int g = 0; g < 4; g++) { float d = acc[t][ct][g] - cv; dsq[g] += d * d; }
      }
#pragma unroll
      for (int m = 1; m < 16; m <<= 1) {
#pragma unroll
        for (int g = 0; g < 4; g++) dsq[g] += __shfl_xor(dsq[g], m, 16);
      }
      if (lnm == 0) {
#pragma unroll
        for (int g = 0; g < 4; g++)
          distS[s2][wave * 32 + t * 16 + lnq * 4 + g] = sqrtf(dsq[g]);
      }
    }
  }
  __syncthreads();
  // softmax over sources (alpha = softmax(-dist))
  if (tid < 128) {
    float dmin = distS[0][tid];
#pragma unroll
    for (int s = 1; s < NS; s++) dmin = fminf(dmin, distS[s][tid]);
    float den = 0.f, e[NS];
#pragma unroll
    for (int s = 0; s < NS; s++) { e[s] = __expf(dmin - distS[s][tid]); den += e[s]; }
    float inv = 1.f / den;
#pragma unroll
    for (int s = 0; s < NS; s++) alphS[s][tid] = e[s] * inv;
  }
  // relu the A fragments in place (h0 = relu(enc), bf16-exact)
#pragma unroll
  for (int t = 0; t < 2; t++) {
#pragma unroll
    for (int ks = 0; ks < 16; ks++) {
      union { bf16x8 v; u16 u[8]; } w; w.v = afrag[t][ks];
#pragma unroll
      for (int j = 0; j < 8; j++) if (w.u[j] & 0x8000) w.u[j] = 0;
      afrag[t][ks] = w.v;
    }
  }
  __syncthreads();

  // ---------------- classifier: per-source MLP + weighted combine ----------------
  float fin[2][4] = {};
#pragma unroll 1
  for (int s = 0; s < NS; s++) {
    __syncthreads();
    b1s[tid] = b1g[s * H + tid];
    b1s[tid + 256] = b1g[s * H + tid + 256];
    float b2v = (lnm < NT) ? b2g[s * NT + lnm] : 0.f;
    f32x4 oacc[2] = {};
#pragma unroll 1
    for (int ch = 0; ch < 8; ch++) {
      f32x4 acc[2][4] = {};
      const u16* wb = W1T + ((size_t)s * H + ch * 64) * H;
      __syncthreads();
      stage64x256(Wst, wb, tid);
      __syncthreads();
      mfma_half(Wst, afrag, 0, lnm, lnq, acc);
      __syncthreads();
      stage64x256(Wst, wb + 256, tid);
      __syncthreads();
      mfma_half(Wst, afrag, 1, lnm, lnq, acc);
      // h1 = relu(acc + b1) -> LDS (bf16)
#pragma unroll
      for (int t = 0; t < 2; t++) {
#pragma unroll
        for (int ct = 0; ct < 4; ct++) {
          int n = ch * 64 + ct * 16 + lnm;
          float bb = b1s[n];
#pragma unroll
          for (int g = 0; g < 4; g++) {
            float v = fmaxf(acc[t][ct][g] + bb, 0.f);
            h1c[(wave * 32 + t * 16 + lnq * 4 + g) * 72 + ct * 16 + lnm] = f2bf(v);
          }
        }
      }
      __syncthreads();
      // second GEMM partial: oacc += h1chunk @ W2T[s][:, chunk]
#pragma unroll
      for (int st = 0; st < 2; st++) {
        bf16x8 bw = *(const bf16x8*)&W2T[((size_t)s * 16 + lnm) * H + ch * 64 + st * 32 + lnq * 8];
#pragma unroll
        for (int t = 0; t < 2; t++) {
          bf16x8 a2 = *(const bf16x8*)&h1c[(wave * 32 + t * 16 + lnm) * 72 + st * 32 + lnq * 8];
          oacc[t] = __builtin_amdgcn_mfma_f32_16x16x32_bf16(a2, bw, oacc[t], 0, 0, 0);
        }
      }
    }
    // sigmoid + alpha-weighted accumulate
#pragma unroll
    for (int t = 0; t < 2; t++) {
#pragma unroll
      for (int g = 0; g < 4; g++) {
        float pre = oacc[t][g] + b2v;
        float sig = 1.f / (1.f + __expf(-pre));
        fin[t][g] += alphS[s][wave * 32 + t * 16 + lnq * 4 + g] * sig;
      }
    }
  }
  // write output rows
  if (lnm < NT) {
#pragma unroll
    for (int t = 0; t < 2; t++) {
#pragma unroll
      for (int g = 0; g < 4; g++) {
        int rg = row0 + wave * 32 + t * 16 + lnq * 4 + g;
        out[(size_t)rg * NT + lnm] = fin[t][g];
      }
    }
  }
}

extern "C" void kernel_launch(void* const* d_in, const int* in_sizes, int n_in,
                              void* d_out, int out_size, void* d_ws, size_t ws_size,
                              hipStream_t stream) {
  const float* enc = (const float*)d_in[0];
  const float* mu  = (const float*)d_in[1];
  const float* Us  = (const float*)d_in[2];
  const float* W1  = (const float*)d_in[3];
  const float* b1  = (const float*)d_in[4];
  const float* W2  = (const float*)d_in[5];
  const float* b2  = (const float*)d_in[6];
  float* out = (float*)d_out;
  char* ws = (char*)d_ws;
  u16* W1T   = (u16*)(ws + WS_W1T);
  u16* UcatT = (u16*)(ws + WS_UCT);
  u16* W2T   = (u16*)(ws + WS_W2T);
  float* cvec = (float*)(ws + WS_CVEC);

  dim3 tb(32, 8, 1);
  transpose_cast<<<dim3(16, 16, 8), tb, 0, stream>>>(W1, W1T, 512, 512, 512);
  transpose_cast<<<dim3(16, 2, 8),  tb, 0, stream>>>(Us, UcatT, 512, 64, 64);
  transpose_cast<<<dim3(16, 1, 8),  tb, 0, stream>>>(W2, W2T, 512, 12, 16);
  compute_c<<<512, 64, 0, stream>>>(mu, Us, cvec);
  moe_main<<<256, 256, 0, stream>>>(enc, W1T, UcatT, W2T, cvec, b1, b2, out);
}

// Round 3
// 380.150 us; speedup vs baseline: 1.4900x; 1.4900x over previous
//
#include <hip/hip_runtime.h>
#include <hip/hip_bf16.h>

typedef unsigned short u16;
typedef __bf16 bf16x8 __attribute__((ext_vector_type(8)));
typedef float f32x4 __attribute__((ext_vector_type(4)));

#define NROWS 32768
#define H 512
#define NS 8
#define NR 64
#define NT 12

// workspace layout (bytes)
#define WS_W1T   0            // [8][512][512] bf16 = 4194304
#define WS_UCT   4194304      // [512][512] bf16    = 524288
#define WS_W2T   4718592      // [8][16][512] bf16  = 131072
#define WS_CVEC  4849664      // [8][64] f32        = 2048
#define WS_ALPH  4851712      // [8][32768] f32     = 1048576

union BFU { __bf16 h; u16 u; };
__device__ __forceinline__ u16 f2bf(float v) { BFU b; b.h = (__bf16)v; return b.u; }

// ---------- prep: batched transpose + cast to bf16 ----------
__global__ __launch_bounds__(256) void transpose_cast(const float* __restrict__ in,
    u16* __restrict__ out, int Rr, int Cc, int Cpad) {
  __shared__ float tile[32][33];
  int b = blockIdx.z, r0 = blockIdx.x * 32, c0 = blockIdx.y * 32;
  int tx = threadIdx.x, ty = threadIdx.y;
#pragma unroll
  for (int i = 0; i < 4; i++) {
    int r = r0 + ty + i * 8, c = c0 + tx;
    float v = 0.f;
    if (r < Rr && c < Cc) v = in[((size_t)b * Rr + r) * Cc + c];
    tile[ty + i * 8][tx] = v;
  }
  __syncthreads();
#pragma unroll
  for (int i = 0; i < 4; i++) {
    int c = c0 + ty + i * 8, r = r0 + tx;
    if (c < Cpad && r < Rr) out[((size_t)b * Cpad + c) * Rr + r] = f2bf(tile[tx][ty + i * 8]);
  }
}

// ---------- prep: c[s][r] = sum_k mu[s][k] * Us[s][k][r] ----------
__global__ __launch_bounds__(64) void compute_c(const float* __restrict__ mu,
                                                const float* __restrict__ Us,
                                                float* __restrict__ cvec) {
  int s = blockIdx.x >> 6, r = blockIdx.x & 63, t = threadIdx.x;
  float acc = 0.f;
#pragma unroll
  for (int k = t; k < H; k += 64) acc += mu[s * H + k] * Us[((size_t)s * H + k) * NR + r];
#pragma unroll
  for (int m = 32; m; m >>= 1) acc += __shfl_xor(acc, m, 64);
  if (t == 0) cvec[blockIdx.x] = acc;
}

// ---------- shared helpers (256-thread blocks) ----------
__device__ __forceinline__ void stage64x256(u16* Wst, const u16* g, int tid) {
#pragma unroll
  for (int i = 0; i < 8; i++) {
    int u = tid + i * 256;
    int n = u >> 5, kk = (u & 31) * 8;
    *(uint4*)&Wst[n * 264 + kk] = *(const uint4*)&g[n * 512 + kk];
  }
}

// 1 m-tile variant (routing)
__device__ __forceinline__ void mfma_half1(const u16* Wst, const bf16x8* af, int half,
                                           int lnm, int lnq, f32x4 acc[4]) {
#pragma unroll
  for (int ks = 0; ks < 8; ks++) {
    bf16x8 a = af[half * 8 + ks];
#pragma unroll
    for (int ct = 0; ct < 4; ct++) {
      bf16x8 b = *(const bf16x8*)&Wst[(ct * 16 + lnm) * 264 + ks * 32 + lnq * 8];
      acc[ct] = __builtin_amdgcn_mfma_f32_16x16x32_bf16(a, b, acc[ct], 0, 0, 0);
    }
  }
}

// 2 m-tile variant (classifier)
__device__ __forceinline__ void mfma_half2(const u16* Wst, const bf16x8 (*af)[16], int half,
                                           int lnm, int lnq, f32x4 acc[2][4]) {
#pragma unroll
  for (int ks = 0; ks < 8; ks++) {
    bf16x8 b[4];
#pragma unroll
    for (int ct = 0; ct < 4; ct++)
      b[ct] = *(const bf16x8*)&Wst[(ct * 16 + lnm) * 264 + ks * 32 + lnq * 8];
#pragma unroll
    for (int ct = 0; ct < 4; ct++) {
#pragma unroll
      for (int t = 0; t < 2; t++)
        acc[t][ct] = __builtin_amdgcn_mfma_f32_16x16x32_bf16(af[t][half * 8 + ks], b[ct],
                                                             acc[t][ct], 0, 0, 0);
    }
  }
}

// ---------- routing kernel: alphaT[s][n] = softmax_s(-dist) ----------
// 512 blocks x 256 thr; 64 rows/block (wave w owns rows w*16..w*16+15)
__global__ __launch_bounds__(256, 2) void routing(
    const float* __restrict__ enc, const u16* __restrict__ UcatT,
    const float* __restrict__ cvec, float* __restrict__ alphT) {
  __shared__ __align__(16) u16 Wst[64 * 264];
  __shared__ float distS[NS][64];
  __shared__ float cst[NS * NR];

  const int tid = threadIdx.x;
  const int wave = tid >> 6, lane = tid & 63;
  const int lnm = lane & 15, lnq = lane >> 4;
  const int row0 = blockIdx.x * 64;

  cst[tid] = cvec[tid];
  cst[tid + 256] = cvec[tid + 256];

  bf16x8 afrag[16];
  {
    const float* rp = enc + (size_t)(row0 + wave * 16 + lnm) * H + lnq * 8;
#pragma unroll
    for (int ks = 0; ks < 16; ks++) {
      float4 x0 = *(const float4*)(rp + ks * 32);
      float4 x1 = *(const float4*)(rp + ks * 32 + 4);
      bf16x8 a;
      a[0] = (__bf16)x0.x; a[1] = (__bf16)x0.y; a[2] = (__bf16)x0.z; a[3] = (__bf16)x0.w;
      a[4] = (__bf16)x1.x; a[5] = (__bf16)x1.y; a[6] = (__bf16)x1.z; a[7] = (__bf16)x1.w;
      afrag[ks] = a;
    }
  }

#pragma unroll 1
  for (int s = 0; s < NS; s++) {
    f32x4 acc[4] = {};
    const u16* ub = UcatT + (size_t)s * 64 * H;
    __syncthreads();
    stage64x256(Wst, ub, tid);
    __syncthreads();
    mfma_half1(Wst, afrag, 0, lnm, lnq, acc);
    __syncthreads();
    stage64x256(Wst, ub + 256, tid);
    __syncthreads();
    mfma_half1(Wst, afrag, 1, lnm, lnq, acc);

    float dsq[4] = {0.f, 0.f, 0.f, 0.f};
#pragma unroll
    for (int ct = 0; ct < 4; ct++) {
      float cv = cst[s * 64 + ct * 16 + lnm];
#pragma unroll
      for (int g = 0; g < 4; g++) { float d = acc[ct][g] - cv; dsq[g] += d * d; }
    }
#pragma unroll
    for (int m = 1; m < 16; m <<= 1) {
#pragma unroll
      for (int g = 0; g < 4; g++) dsq[g] += __shfl_xor(dsq[g], m, 16);
    }
    if (lnm == 0) {
#pragma unroll
      for (int g = 0; g < 4; g++) distS[s][wave * 16 + lnq * 4 + g] = sqrtf(dsq[g]);
    }
  }
  __syncthreads();
  if (tid < 64) {
    float dmin = distS[0][tid];
#pragma unroll
    for (int s = 1; s < NS; s++) dmin = fminf(dmin, distS[s][tid]);
    float den = 0.f, e[NS];
#pragma unroll
    for (int s = 0; s < NS; s++) { e[s] = __expf(dmin - distS[s][tid]); den += e[s]; }
    float inv = 1.f / den;
#pragma unroll
    for (int s = 0; s < NS; s++) alphT[(size_t)s * NROWS + row0 + tid] = e[s] * inv;
  }
}

// ---------- main classifier: 512 blocks = 256 row-blocks x 2 source-groups ----------
// 4 waves x 2 m-tiles = 128 rows/block, 4 sources/block, atomicAdd combine
__global__ __launch_bounds__(256, 2) void moe_main(
    const float* __restrict__ enc, const u16* __restrict__ W1T,
    const u16* __restrict__ W2T, const float* __restrict__ alphT,
    const float* __restrict__ b1g, const float* __restrict__ b2g,
    float* __restrict__ out) {
  __shared__ __align__(16) u16 Wst[64 * 264];    // 33792 B
  __shared__ __align__(16) u16 h1c[128 * 72];    // 18432 B
  __shared__ float b1s[H];                       // 2048 B
  __shared__ float alphS[4][128];                // 2048 B   (total 56320 B -> 2 blocks/CU)

  const int tid = threadIdx.x;
  const int wave = tid >> 6, lane = tid & 63;
  const int lnm = lane & 15, lnq = lane >> 4;
  const int rb = blockIdx.x >> 1, sg = blockIdx.x & 1;
  const int row0 = rb * 128, sbase = sg * 4;

  // stage alphas for this block's rows & sources
#pragma unroll
  for (int i = 0; i < 2; i++) {
    int u = tid + i * 256, j = u >> 7, r = u & 127;
    alphS[j][r] = alphT[(size_t)(sbase + j) * NROWS + row0 + r];
  }

  // A fragments: h0 = relu(enc) in bf16, 2 m-tiles x 16 k-steps
  bf16x8 afrag[2][16];
#pragma unroll
  for (int t = 0; t < 2; t++) {
    const float* rp = enc + (size_t)(row0 + wave * 32 + t * 16 + lnm) * H + lnq * 8;
#pragma unroll
    for (int ks = 0; ks < 16; ks++) {
      float4 x0 = *(const float4*)(rp + ks * 32);
      float4 x1 = *(const float4*)(rp + ks * 32 + 4);
      bf16x8 a;
      a[0] = (__bf16)fmaxf(x0.x, 0.f); a[1] = (__bf16)fmaxf(x0.y, 0.f);
      a[2] = (__bf16)fmaxf(x0.z, 0.f); a[3] = (__bf16)fmaxf(x0.w, 0.f);
      a[4] = (__bf16)fmaxf(x1.x, 0.f); a[5] = (__bf16)fmaxf(x1.y, 0.f);
      a[6] = (__bf16)fmaxf(x1.z, 0.f); a[7] = (__bf16)fmaxf(x1.w, 0.f);
      afrag[t][ks] = a;
    }
  }

  float fin[2][4] = {};
#pragma unroll 1
  for (int j = 0; j < 4; j++) {
    const int s = sbase + j;
    __syncthreads();
    b1s[tid] = b1g[s * H + tid];
    b1s[tid + 256] = b1g[s * H + tid + 256];
    float b2v = (lnm < NT) ? b2g[s * NT + lnm] : 0.f;
    f32x4 oacc[2] = {};
#pragma unroll 1
    for (int ch = 0; ch < 8; ch++) {
      f32x4 acc[2][4] = {};
      const u16* wb = W1T + ((size_t)s * H + ch * 64) * H;
      __syncthreads();
      stage64x256(Wst, wb, tid);
      __syncthreads();
      mfma_half2(Wst, afrag, 0, lnm, lnq, acc);
      __syncthreads();
      stage64x256(Wst, wb + 256, tid);
      __syncthreads();
      mfma_half2(Wst, afrag, 1, lnm, lnq, acc);
      // h1 = relu(acc + b1) -> LDS (bf16)
#pragma unroll
      for (int t = 0; t < 2; t++) {
#pragma unroll
        for (int ct = 0; ct < 4; ct++) {
          float bb = b1s[ch * 64 + ct * 16 + lnm];
#pragma unroll
          for (int g = 0; g < 4; g++) {
            float v = fmaxf(acc[t][ct][g] + bb, 0.f);
            h1c[(wave * 32 + t * 16 + lnq * 4 + g) * 72 + ct * 16 + lnm] = f2bf(v);
          }
        }
      }
      __syncthreads();
      // second GEMM partial: oacc += h1chunk @ W2T[s][:, chunk]
#pragma unroll
      for (int st = 0; st < 2; st++) {
        bf16x8 bw = *(const bf16x8*)&W2T[((size_t)s * 16 + lnm) * H + ch * 64 + st * 32 + lnq * 8];
#pragma unroll
        for (int t = 0; t < 2; t++) {
          bf16x8 a2 = *(const bf16x8*)&h1c[(wave * 32 + t * 16 + lnm) * 72 + st * 32 + lnq * 8];
          oacc[t] = __builtin_amdgcn_mfma_f32_16x16x32_bf16(a2, bw, oacc[t], 0, 0, 0);
        }
      }
    }
    // sigmoid + alpha-weighted accumulate (partial over this block's sources)
#pragma unroll
    for (int t = 0; t < 2; t++) {
#pragma unroll
      for (int g = 0; g < 4; g++) {
        float pre = oacc[t][g] + b2v;
        float sig = 1.f / (1.f + __expf(-pre));
        fin[t][g] += alphS[j][wave * 32 + t * 16 + lnq * 4 + g] * sig;
      }
    }
  }
  // combine partials across the 2 source-groups
  if (lnm < NT) {
#pragma unroll
    for (int t = 0; t < 2; t++) {
#pragma unroll
      for (int g = 0; g < 4; g++) {
        int rg = row0 + wave * 32 + t * 16 + lnq * 4 + g;
        atomicAdd(&out[(size_t)rg * NT + lnm], fin[t][g]);
      }
    }
  }
}

extern "C" void kernel_launch(void* const* d_in, const int* in_sizes, int n_in,
                              void* d_out, int out_size, void* d_ws, size_t ws_size,
                              hipStream_t stream) {
  const float* enc = (const float*)d_in[0];
  const float* mu  = (const float*)d_in[1];
  const float* Us  = (const float*)d_in[2];
  const float* W1  = (const float*)d_in[3];
  const float* b1  = (const float*)d_in[4];
  const float* W2  = (const float*)d_in[5];
  const float* b2  = (const float*)d_in[6];
  float* out = (float*)d_out;
  char* ws = (char*)d_ws;
  u16* W1T    = (u16*)(ws + WS_W1T);
  u16* UcatT  = (u16*)(ws + WS_UCT);
  u16* W2T    = (u16*)(ws + WS_W2T);
  float* cvec = (float*)(ws + WS_CVEC);
  float* alphT = (float*)(ws + WS_ALPH);

  dim3 tb(32, 8, 1);
  transpose_cast<<<dim3(16, 16, 8), tb, 0, stream>>>(W1, W1T, 512, 512, 512);
  transpose_cast<<<dim3(16, 2, 8),  tb, 0, stream>>>(Us, UcatT, 512, 64, 64);
  transpose_cast<<<dim3(16, 1, 8),  tb, 0, stream>>>(W2, W2T, 512, 12, 16);
  compute_c<<<512, 64, 0, stream>>>(mu, Us, cvec);
  routing<<<512, 256, 0, stream>>>(enc, UcatT, cvec, alphT);
  hipMemsetAsync(out, 0, (size_t)out_size * sizeof(float), stream);
  moe_main<<<512, 256, 0, stream>>>(enc, W1T, W2T, alphT, b1, b2, out);
}

// Round 4
// 305.831 us; speedup vs baseline: 1.8521x; 1.2430x over previous
//
#include <hip/hip_runtime.h>
#include <hip/hip_bf16.h>

typedef unsigned short u16;
typedef __bf16 bf16x8 __attribute__((ext_vector_type(8)));
typedef float f32x4 __attribute__((ext_vector_type(4)));

#define NROWS 32768
#define H 512
#define NS 8
#define NR 64
#define NT 12

// workspace layout (bytes)
#define WS_W1T   0            // [8][512 n][512 k] bf16 = 4194304
#define WS_UCT   4194304      // [512 r][512 k] bf16    = 524288
#define WS_W2T   4718592      // [8][16 t][512 k] bf16  = 131072
#define WS_CVEC  4849664      // [8][64] f32            = 2048
#define WS_ALPH  4851712      // [8][32768] f32         = 1048576

union BFU { __bf16 h; u16 u; };
__device__ __forceinline__ u16 f2bf(float v) { BFU b; b.h = (__bf16)v; return b.u; }

__device__ __forceinline__ void gload16(const u16* g, u16* l) {
  __builtin_amdgcn_global_load_lds(
      (const __attribute__((address_space(1))) unsigned int*)g,
      (__attribute__((address_space(3))) unsigned int*)l, 16, 0, 0);
}

// stage one 32-row x 512-u16 chunk (row stride 512 u16 in global) into 32 KB LDS,
// XOR-swizzled: LDS 16B-unit v of row r holds global k-unit (v ^ (r&7)) of row r.
__device__ __forceinline__ void stage32(const u16* __restrict__ g, u16* l, int wave, int lane) {
#pragma unroll
  for (int i = 0; i < 8; i++) {
    int r = wave * 8 + i;
    gload16(g + (size_t)r * 512 + (size_t)((lane ^ (r & 7)) * 8), l + r * 512);
  }
}

// ---------- prep: batched transpose + cast to bf16 ----------
__global__ __launch_bounds__(256) void transpose_cast(const float* __restrict__ in,
    u16* __restrict__ out, int Rr, int Cc, int Cpad) {
  __shared__ float tile[32][33];
  int b = blockIdx.z, r0 = blockIdx.x * 32, c0 = blockIdx.y * 32;
  int tx = threadIdx.x, ty = threadIdx.y;
#pragma unroll
  for (int i = 0; i < 4; i++) {
    int r = r0 + ty + i * 8, c = c0 + tx;
    float v = 0.f;
    if (r < Rr && c < Cc) v = in[((size_t)b * Rr + r) * Cc + c];
    tile[ty + i * 8][tx] = v;
  }
  __syncthreads();
#pragma unroll
  for (int i = 0; i < 4; i++) {
    int c = c0 + ty + i * 8, r = r0 + tx;
    if (c < Cpad && r < Rr) out[((size_t)b * Cpad + c) * Rr + r] = f2bf(tile[tx][ty + i * 8]);
  }
}

// ---------- prep: c[s][r] = sum_k mu[s][k] * Us[s][k][r] ----------
__global__ __launch_bounds__(64) void compute_c(const float* __restrict__ mu,
                                                const float* __restrict__ Us,
                                                float* __restrict__ cvec) {
  int s = blockIdx.x >> 6, r = blockIdx.x & 63, t = threadIdx.x;
  float acc = 0.f;
#pragma unroll
  for (int k = t; k < H; k += 64) acc += mu[s * H + k] * Us[((size_t)s * H + k) * NR + r];
#pragma unroll
  for (int m = 32; m; m >>= 1) acc += __shfl_xor(acc, m, 64);
  if (t == 0) cvec[blockIdx.x] = acc;
}

// ---------- routing: alphaT[s][n] = softmax_s(-dist), 512 blocks x 256 thr, 64 rows/blk ----------
__global__ __launch_bounds__(256, 2) void routing(
    const float* __restrict__ enc, const u16* __restrict__ UcatT,
    const float* __restrict__ cvec, float* __restrict__ alphT) {
  __shared__ __align__(16) u16 Wst[2][32 * 512];   // 65536 B
  __shared__ float distS[NS][64];                  // 2048 B

  const int tid = threadIdx.x;
  const int wave = tid >> 6, lane = tid & 63;
  const int lnm = lane & 15, lnq = lane >> 4;
  const int row0 = blockIdx.x * 64;

  // A fragments: raw enc, bf16
  bf16x8 afrag[16];
  {
    const float* rp = enc + (size_t)(row0 + wave * 16 + lnm) * H + lnq * 8;
#pragma unroll
    for (int ks = 0; ks < 16; ks++) {
      float4 x0 = *(const float4*)(rp + ks * 32);
      float4 x1 = *(const float4*)(rp + ks * 32 + 4);
      bf16x8 a;
      a[0] = (__bf16)x0.x; a[1] = (__bf16)x0.y; a[2] = (__bf16)x0.z; a[3] = (__bf16)x0.w;
      a[4] = (__bf16)x1.x; a[5] = (__bf16)x1.y; a[6] = (__bf16)x1.z; a[7] = (__bf16)x1.w;
      afrag[ks] = a;
    }
  }

  stage32(UcatT, Wst[0], wave, lane);
  float dsq[4] = {0.f, 0.f, 0.f, 0.f};
#pragma unroll 1
  for (int q = 0; q < 16; q++) {
    int s = q >> 1, half = q & 1;
    __syncthreads();
    if (q < 15) stage32(UcatT + (size_t)(q + 1) * 32 * 512, Wst[(q + 1) & 1], wave, lane);
    const u16* buf = Wst[q & 1];
    f32x4 acc[2] = {};
#pragma unroll
    for (int ks = 0; ks < 16; ks++) {
      int uu = ((ks * 4 + lnq) ^ (lnm & 7)) * 8;
      bf16x8 b0 = *(const bf16x8*)&buf[lnm * 512 + uu];
      bf16x8 b1v = *(const bf16x8*)&buf[(16 + lnm) * 512 + uu];
      acc[0] = __builtin_amdgcn_mfma_f32_16x16x32_bf16(afrag[ks], b0, acc[0], 0, 0, 0);
      acc[1] = __builtin_amdgcn_mfma_f32_16x16x32_bf16(afrag[ks], b1v, acc[1], 0, 0, 0);
    }
#pragma unroll
    for (int ct = 0; ct < 2; ct++) {
      float cv = cvec[s * 64 + half * 32 + ct * 16 + lnm];
#pragma unroll
      for (int g = 0; g < 4; g++) { float d = acc[ct][g] - cv; dsq[g] += d * d; }
    }
    if (half == 1) {
#pragma unroll
      for (int m = 1; m < 16; m <<= 1) {
#pragma unroll
        for (int g = 0; g < 4; g++) dsq[g] += __shfl_xor(dsq[g], m, 16);
      }
      if (lnm == 0) {
#pragma unroll
        for (int g = 0; g < 4; g++) distS[s][wave * 16 + lnq * 4 + g] = sqrtf(dsq[g]);
      }
#pragma unroll
      for (int g = 0; g < 4; g++) dsq[g] = 0.f;
    }
  }
  __syncthreads();
  if (tid < 64) {
    float dmin = distS[0][tid];
#pragma unroll
    for (int s = 1; s < NS; s++) dmin = fminf(dmin, distS[s][tid]);
    float den = 0.f, e[NS];
#pragma unroll
    for (int s = 0; s < NS; s++) { e[s] = __expf(dmin - distS[s][tid]); den += e[s]; }
    float inv = 1.f / den;
#pragma unroll
    for (int s = 0; s < NS; s++) alphT[(size_t)s * NROWS + row0 + tid] = e[s] * inv;
  }
}

// ---------- main classifier: 512 blocks = 256 row-blocks x 2 source-groups ----------
// 4 waves x 2 m-tiles = 128 rows/block, 4 sources/block; dbuf async K-loop, 1 barrier/chunk
__global__ __launch_bounds__(256, 2) void moe_main(
    const float* __restrict__ enc, const u16* __restrict__ W1T,
    const u16* __restrict__ W2T, const float* __restrict__ alphT,
    const float* __restrict__ b1g, const float* __restrict__ b2g,
    float* __restrict__ out) {
  __shared__ __align__(16) u16 Wst[2][32 * 512];   // 65536 B
  __shared__ __align__(16) u16 h1c[128 * 48];      // 12288 B (stride 48 u16: 16B-aligned rows)
  __shared__ float alphS[4][128];                  // 2048 B  (total 79872 B -> 2 blocks/CU)

  const int tid = threadIdx.x;
  const int wave = tid >> 6, lane = tid & 63;
  const int lnm = lane & 15, lnq = lane >> 4;
  const int rb = blockIdx.x >> 1, sg = blockIdx.x & 1;
  const int row0 = rb * 128, sbase = sg * 4;

  // stage alphas for this block's rows & sources
#pragma unroll
  for (int i = 0; i < 2; i++) {
    int u = tid + i * 256, j = u >> 7, r = u & 127;
    alphS[j][r] = alphT[(size_t)(sbase + j) * NROWS + row0 + r];
  }

  // A fragments: h0 = relu(enc) in bf16, 2 m-tiles x 16 k-steps
  bf16x8 afrag[2][16];
#pragma unroll
  for (int t = 0; t < 2; t++) {
    const float* rp = enc + (size_t)(row0 + wave * 32 + t * 16 + lnm) * H + lnq * 8;
#pragma unroll
    for (int ks = 0; ks < 16; ks++) {
      float4 x0 = *(const float4*)(rp + ks * 32);
      float4 x1 = *(const float4*)(rp + ks * 32 + 4);
      bf16x8 a;
      a[0] = (__bf16)fmaxf(x0.x, 0.f); a[1] = (__bf16)fmaxf(x0.y, 0.f);
      a[2] = (__bf16)fmaxf(x0.z, 0.f); a[3] = (__bf16)fmaxf(x0.w, 0.f);
      a[4] = (__bf16)fmaxf(x1.x, 0.f); a[5] = (__bf16)fmaxf(x1.y, 0.f);
      a[6] = (__bf16)fmaxf(x1.z, 0.f); a[7] = (__bf16)fmaxf(x1.w, 0.f);
      afrag[t][ks] = a;
    }
  }

  stage32(W1T + (size_t)sbase * 512 * 512, Wst[0], wave, lane);
  f32x4 oacc[2] = {};
  float fin[2][4] = {};
#pragma unroll 1
  for (int q = 0; q < 64; q++) {
    const int j = q >> 4, ch = q & 15;
    const int s = sbase + j;
    __syncthreads();                         // buf[q&1] loads drained; buf[(q+1)&1] free
    if (q < 63) {
      int q1 = q + 1;
      const u16* nb = W1T + ((size_t)(sbase + (q1 >> 4)) * 512 + (q1 & 15) * 32) * 512;
      stage32(nb, Wst[q1 & 1], wave, lane);  // async, overlaps compute below
    }
    const u16* buf = Wst[q & 1];
    f32x4 acc[2][2] = {};
#pragma unroll
    for (int ks = 0; ks < 16; ks++) {
      int uu = ((ks * 4 + lnq) ^ (lnm & 7)) * 8;
      bf16x8 b0 = *(const bf16x8*)&buf[lnm * 512 + uu];
      bf16x8 b1v = *(const bf16x8*)&buf[(16 + lnm) * 512 + uu];
#pragma unroll
      for (int t = 0; t < 2; t++) {
        acc[t][0] = __builtin_amdgcn_mfma_f32_16x16x32_bf16(afrag[t][ks], b0, acc[t][0], 0, 0, 0);
        acc[t][1] = __builtin_amdgcn_mfma_f32_16x16x32_bf16(afrag[t][ks], b1v, acc[t][1], 0, 0, 0);
      }
    }
    // h1 = relu(acc + b1) -> wave-private LDS rows (no barrier needed)
    float bb0 = b1g[s * H + ch * 32 + lnm];
    float bb1 = b1g[s * H + ch * 32 + 16 + lnm];
#pragma unroll
    for (int t = 0; t < 2; t++) {
#pragma unroll
      for (int g = 0; g < 4; g++) {
        int rr = wave * 32 + t * 16 + lnq * 4 + g;
        h1c[rr * 48 + lnm]      = f2bf(fmaxf(acc[t][0][g] + bb0, 0.f));
        h1c[rr * 48 + 16 + lnm] = f2bf(fmaxf(acc[t][1][g] + bb1, 0.f));
      }
    }
    // second GEMM partial over this 32-col K-window
    bf16x8 bw = *(const bf16x8*)&W2T[((size_t)s * 16 + lnm) * 512 + ch * 32 + lnq * 8];
#pragma unroll
    for (int t = 0; t < 2; t++) {
      bf16x8 a2 = *(const bf16x8*)&h1c[(wave * 32 + t * 16 + lnm) * 48 + lnq * 8];
      oacc[t] = __builtin_amdgcn_mfma_f32_16x16x32_bf16(a2, bw, oacc[t], 0, 0, 0);
    }
    if (ch == 15) {   // end of source: sigmoid + alpha-weighted accumulate
      float b2v = (lnm < NT) ? b2g[s * NT + lnm] : 0.f;
#pragma unroll
      for (int t = 0; t < 2; t++) {
#pragma unroll
        for (int g = 0; g < 4; g++) {
          float pre = oacc[t][g] + b2v;
          float sig = 1.f / (1.f + __expf(-pre));
          fin[t][g] += alphS[j][wave * 32 + t * 16 + lnq * 4 + g] * sig;
        }
        oacc[t] = (f32x4){0.f, 0.f, 0.f, 0.f};
      }
    }
  }
  // combine partials across the 2 source-groups
  if (lnm < NT) {
#pragma unroll
    for (int t = 0; t < 2; t++) {
#pragma unroll
      for (int g = 0; g < 4; g++) {
        int rg = row0 + wave * 32 + t * 16 + lnq * 4 + g;
        atomicAdd(&out[(size_t)rg * NT + lnm], fin[t][g]);
      }
    }
  }
}

extern "C" void kernel_launch(void* const* d_in, const int* in_sizes, int n_in,
                              void* d_out, int out_size, void* d_ws, size_t ws_size,
                              hipStream_t stream) {
  const float* enc = (const float*)d_in[0];
  const float* mu  = (const float*)d_in[1];
  const float* Us  = (const float*)d_in[2];
  const float* W1  = (const float*)d_in[3];
  const float* b1  = (const float*)d_in[4];
  const float* W2  = (const float*)d_in[5];
  const float* b2  = (const float*)d_in[6];
  float* out = (float*)d_out;
  char* ws = (char*)d_ws;
  u16* W1T    = (u16*)(ws + WS_W1T);
  u16* UcatT  = (u16*)(ws + WS_UCT);
  u16* W2T    = (u16*)(ws + WS_W2T);
  float* cvec = (float*)(ws + WS_CVEC);
  float* alphT = (float*)(ws + WS_ALPH);

  dim3 tb(32, 8, 1);
  transpose_cast<<<dim3(16, 16, 8), tb, 0, stream>>>(W1, W1T, 512, 512, 512);
  transpose_cast<<<dim3(16, 2, 8),  tb, 0, stream>>>(Us, UcatT, 512, 64, 64);
  transpose_cast<<<dim3(16, 1, 8),  tb, 0, stream>>>(W2, W2T, 512, 12, 16);
  compute_c<<<512, 64, 0, stream>>>(mu, Us, cvec);
  routing<<<512, 256, 0, stream>>>(enc, UcatT, cvec, alphT);
  hipMemsetAsync(out, 0, (size_t)out_size * sizeof(float), stream);
  moe_main<<<512, 256, 0, stream>>>(enc, W1T, W2T, alphT, b1, b2, out);
}